// Round 12
// baseline (104.146 us; speedup 1.0000x reference)
//
#include <hip/hip_runtime.h>
#include <math.h>

#define NDIRS 64
#define NBIN 65
#define HSTRIDE 65             // row stride = output stride; next row's bin-0
                               // doubles as spill guard (provably only +0.0)
#define HIST1 4164             // 64*65 + guard, padded %4==0 for vec zeroing
#define STAGEF 512             // 64 cells * 8 aggregates per wave (f32)
#define THREADS 256
#define WPB 4
#define SPW 2
#define NBLK 512               // 512*4*2 = 4096 strips
#define ROWF (NDIRS*NBIN)      // 4160
#define MROWS 64               // mid rows (8 blocks share one row via atomics)

static constexpr float INV = 0.28867513459481287f; // 1/(2*sqrt(3))

__global__ __launch_bounds__(THREADS) void wect_hist(
    const float* __restrict__ x, const float* __restrict__ dirs,
    float* __restrict__ mid) {
  __shared__ float hist[WPB * HIST1];     // 66,624 B
  __shared__ float stage[WPB * STAGEF];   //  8,192 B (74.8 KB -> 2 blocks/CU)
  const int tid = threadIdx.x;
  const int lane = tid & 63;
  const int wid  = tid >> 6;

  float4* h4 = (float4*)hist;
  for (int idx = tid; idx < WPB * HIST1 / 4; idx += THREADS)
    h4[idx] = make_float4(0.f, 0.f, 0.f, 0.f);
  __syncthreads();

  // lane = DIRECTION constants (pre-scaled by 1/dh)
  const float D0 = dirs[3*lane+0] * INV;
  const float D1 = dirs[3*lane+1] * INV;
  const float D2 = dirs[3*lane+2] * INV;
  const float Q1 = fmaxf(D0, 0.f);
  const float Q2 = fmaxf(D1, 0.f);
  const float Q3 = fmaxf(D2, 0.f);
  const float Q4 = Q2 + Q3;
  const float Q5 = Q1 + Q3;
  const float Q6 = Q1 + Q2;
  const float Q7 = Q1 + Q2 + Q3;

  float* __restrict__ myrow = hist + wid * HIST1 + lane * HSTRIDE;
  float4* __restrict__ mystage = (float4*)(stage + wid * STAGEF);

  for (int s = 0; s < SPW; ++s) {
    const int strip = (blockIdx.x * WPB + wid) * SPW + s;   // [0,4096)
    const int i = strip >> 6, j = strip & 63;
    const int l = lane;                       // lane = CELL for load phase
    const float* p = x + (strip << 6) + l;
    const int dL = (l < 63) ? 1 : 0;
    const int dJ = (j < 63) ? 64 : 0;
    const int dI = (i < 63) ? 4096 : 0;
    const bool iv = dI != 0, jv = dJ != 0, lv = dL != 0;

    const float x000 = p[0],       x001 = p[dL];
    const float x010 = p[dJ],      x011 = p[dJ+dL];
    const float x100 = p[dI],      x101 = p[dI+dL];
    const float x110 = p[dI+dJ],   x111 = p[dI+dJ+dL];

    const float e0m = fmaxf(x000, x100);
    const float e1m = fmaxf(x000, x010);
    const float e2m = fmaxf(x000, x001);
    const float s12 = fmaxf(fmaxf(e1m, x001), x011);
    const float s02 = fmaxf(fmaxf(e0m, x001), x101);
    const float s01 = fmaxf(fmaxf(e0m, x010), x110);
    const float cc  = fmaxf(fmaxf(s01, fmaxf(x001, x101)), fmaxf(x011, x111));

    const float v1 = iv ? -e0m : 0.f;
    const float v2 = jv ? -e1m : 0.f;
    const float v3 = lv ? -e2m : 0.f;
    const float v4 = (jv && lv) ? s12 : 0.f;
    const float v5 = (iv && lv) ? s02 : 0.f;
    const float v6 = (iv && jv) ? s01 : 0.f;
    const float v7 = (iv && jv && lv) ? -cc : 0.f;
    const float T  = x000 + v1+v2+v3+v4+v5+v6+v7;

    // stage this wave's 64 cells' aggregates: 2x ds_write_b128 per lane
    // (f32 — R11 showed fp16 packing is neutral; keep the proven R9 loop)
    mystage[2*lane]     = make_float4(T,  v1, v2, v3);
    mystage[2*lane + 1] = make_float4(v4, v5, v6, v7);

    const float u0 = (float)i * D0 + (float)j * D1;   // per-lane(dir)

    #pragma unroll 8
    for (int t = 0; t < 64; ++t) {
      const float4 A = mystage[2*t];      // T, v1, v2, v3 (same-addr broadcast)
      const float4 B = mystage[2*t + 1];  // v4, v5, v6, v7
      const float u  = fmaf((float)t, D2, u0);
      const float bf = ceilf(u);
      const float fr = bf - u;                 // [0,1)
      const int   ib = (int)bf + 32;           // provably in [1,64]
      float S = 0.f;
      S += (Q1 > fr) ? A.y : 0.f;
      S += (Q2 > fr) ? A.z : 0.f;
      S += (Q3 > fr) ? A.w : 0.f;
      S += (Q4 > fr) ? B.x : 0.f;
      S += (Q5 > fr) ? B.y : 0.f;
      S += (Q6 > fr) ? B.z : 0.f;
      S += (Q7 > fr) ? B.w : 0.f;
      float* a = myrow + ib;                   // lane-private row: no conflicts
      const float r0 = a[0], r1 = a[1];        // same-wave DS ops are in-order
      a[0] = r0 + (A.x - S);
      a[1] = r1 + S;                           // ib==64 -> S==0 (height bound)
    }
  }

  __syncthreads();
  // flush: sum 4 wave-private copies via b128 reads, atomically into mid row
  // (64 rows, 8 blocks/row -> low contention, proven in R4)
  float* __restrict__ mrow = mid + (blockIdx.x & (MROWS - 1)) * ROWF;
  for (int q = tid; q < ROWF / 4; q += THREADS) {
    const float4 a = *(const float4*)&hist[4 * q];
    const float4 b = *(const float4*)&hist[HIST1 + 4 * q];
    const float4 c = *(const float4*)&hist[2 * HIST1 + 4 * q];
    const float4 d = *(const float4*)&hist[3 * HIST1 + 4 * q];
    unsafeAtomicAdd(&mrow[4 * q + 0], a.x + b.x + c.x + d.x);
    unsafeAtomicAdd(&mrow[4 * q + 1], a.y + b.y + c.y + d.y);
    unsafeAtomicAdd(&mrow[4 * q + 2], a.z + b.z + c.z + d.z);
    unsafeAtomicAdd(&mrow[4 * q + 3], a.w + b.w + c.w + d.w);
  }
}

__global__ __launch_bounds__(512) void wect_scan(
    const float* __restrict__ mid, float* __restrict__ out) {
  __shared__ float red[8 * NBIN];
  __shared__ float s[NBIN];
  const int k = blockIdx.x, tid = threadIdx.x;
  for (int z = tid; z < 8 * NBIN; z += 512) {   // 520 items > 512 thr: stride
    const int g = z / NBIN, c = z - g * NBIN;
    float v = 0.f;
    #pragma unroll
    for (int r = g; r < MROWS; r += 8) v += mid[r * ROWF + k * NBIN + c];
    red[z] = v;
  }
  __syncthreads();
  if (tid < NBIN) {
    float v = 0.f;
    #pragma unroll
    for (int gg = 0; gg < 8; ++gg) v += red[gg * NBIN + tid];
    s[tid] = v;
  }
  __syncthreads();
  for (int off = 1; off < NBIN; off <<= 1) {
    float a = 0.f;
    if (tid < NBIN && tid >= off) a = s[tid - off];
    __syncthreads();
    if (tid < NBIN && tid >= off) s[tid] += a;
    __syncthreads();
  }
  if (tid < NBIN) out[k * NBIN + tid] = s[tid];
}

extern "C" void kernel_launch(void* const* d_in, const int* in_sizes, int n_in,
                              void* d_out, int out_size, void* d_ws, size_t ws_size,
                              hipStream_t stream) {
  const float* x = (const float*)d_in[0];
  const float* dirs = (const float*)d_in[1];
  float* out = (float*)d_out;
  float* mid = (float*)d_ws;                   // 64*4160 floats = 1.06 MB

  hipMemsetAsync(mid, 0, MROWS * ROWF * sizeof(float), stream);
  wect_hist<<<NBLK, THREADS, 0, stream>>>(x, dirs, mid);
  wect_scan<<<NDIRS, 512, 0, stream>>>(mid, out);
}

// Round 13
// 83.441 us; speedup vs baseline: 1.2481x; 1.2481x over previous
//
#include <hip/hip_runtime.h>
#include <math.h>

#define NDIRS 64
#define NBIN 65
#define HIST1 4224             // 66 bins x 64 lanes (bin-major), per wave
#define STAGEF 512             // 64 cells * 8 aggregates per wave (f32)
#define THREADS 256
#define WPB 4
#define SPW 2
#define NBLK 512               // 512*4*2 = 4096 strips
#define ROWF (NDIRS*NBIN)      // 4160 (= bins 0..64 x 64 dirs, bin-major)
#define MROWS 64               // rows after reduceA

static constexpr float INV = 0.28867513459481287f; // 1/(2*sqrt(3))

__global__ __launch_bounds__(THREADS) void wect_hist(
    const float* __restrict__ x, const float* __restrict__ dirs,
    float* __restrict__ accum) {
  __shared__ float hist[WPB * HIST1];     // 67,584 B  (bin-major per wave)
  __shared__ float stage[WPB * STAGEF];   //  8,192 B  (75.8 KB -> 2 blocks/CU)
  const int tid = threadIdx.x;
  const int lane = tid & 63;
  const int wid  = tid >> 6;

  float4* h4 = (float4*)hist;
  for (int idx = tid; idx < WPB * HIST1 / 4; idx += THREADS)
    h4[idx] = make_float4(0.f, 0.f, 0.f, 0.f);
  __syncthreads();

  // lane = DIRECTION constants (pre-scaled by 1/dh)
  const float D0 = dirs[3*lane+0] * INV;
  const float D1 = dirs[3*lane+1] * INV;
  const float D2 = dirs[3*lane+2] * INV;
  const float Q1 = fmaxf(D0, 0.f);
  const float Q2 = fmaxf(D1, 0.f);
  const float Q3 = fmaxf(D2, 0.f);
  const float Q4 = Q2 + Q3;
  const float Q5 = Q1 + Q3;
  const float Q6 = Q1 + Q2;
  const float Q7 = Q1 + Q2 + Q3;

  // bin-major: address = bin*64 + lane -> bank = lane%32 (2-way = free),
  // INDEPENDENT of bin: kills the 5.4M SQ_LDS_BANK_CONFLICT seen in R12.
  float* __restrict__ myh = hist + wid * HIST1 + lane;
  float4* __restrict__ mystage = (float4*)(stage + wid * STAGEF);

  for (int s = 0; s < SPW; ++s) {
    const int strip = (blockIdx.x * WPB + wid) * SPW + s;   // [0,4096)
    const int i = strip >> 6, j = strip & 63;
    const int l = lane;                       // lane = CELL for load phase
    const float* p = x + (strip << 6) + l;
    const int dL = (l < 63) ? 1 : 0;
    const int dJ = (j < 63) ? 64 : 0;
    const int dI = (i < 63) ? 4096 : 0;
    const bool iv = dI != 0, jv = dJ != 0, lv = dL != 0;

    const float x000 = p[0],       x001 = p[dL];
    const float x010 = p[dJ],      x011 = p[dJ+dL];
    const float x100 = p[dI],      x101 = p[dI+dL];
    const float x110 = p[dI+dJ],   x111 = p[dI+dJ+dL];

    const float e0m = fmaxf(x000, x100);
    const float e1m = fmaxf(x000, x010);
    const float e2m = fmaxf(x000, x001);
    const float s12 = fmaxf(fmaxf(e1m, x001), x011);
    const float s02 = fmaxf(fmaxf(e0m, x001), x101);
    const float s01 = fmaxf(fmaxf(e0m, x010), x110);
    const float cc  = fmaxf(fmaxf(s01, fmaxf(x001, x101)), fmaxf(x011, x111));

    const float v1 = iv ? -e0m : 0.f;
    const float v2 = jv ? -e1m : 0.f;
    const float v3 = lv ? -e2m : 0.f;
    const float v4 = (jv && lv) ? s12 : 0.f;
    const float v5 = (iv && lv) ? s02 : 0.f;
    const float v6 = (iv && jv) ? s01 : 0.f;
    const float v7 = (iv && jv && lv) ? -cc : 0.f;
    const float T  = x000 + v1+v2+v3+v4+v5+v6+v7;

    // stage this wave's 64 cells' aggregates: 2x ds_write_b128 per lane
    mystage[2*lane]     = make_float4(T,  v1, v2, v3);
    mystage[2*lane + 1] = make_float4(v4, v5, v6, v7);

    const float u0 = (float)i * D0 + (float)j * D1;   // per-lane(dir)

    #pragma unroll 8
    for (int t = 0; t < 64; ++t) {
      const float4 A = mystage[2*t];      // T, v1, v2, v3 (same-addr broadcast)
      const float4 B = mystage[2*t + 1];  // v4, v5, v6, v7
      const float u  = fmaf((float)t, D2, u0);
      const float bf = ceilf(u);
      const float fr = bf - u;                 // [0,1)
      const int   ib = (int)bf + 32;           // provably in [1,64]
      float S = 0.f;
      S += (Q1 > fr) ? A.y : 0.f;
      S += (Q2 > fr) ? A.z : 0.f;
      S += (Q3 > fr) ? A.w : 0.f;
      S += (Q4 > fr) ? B.x : 0.f;
      S += (Q5 > fr) ? B.y : 0.f;
      S += (Q6 > fr) ? B.z : 0.f;
      S += (Q7 > fr) ? B.w : 0.f;
      float* a = myh + (ib << 6);              // bank = lane%32, conflict-free
      const float r0 = a[0], r1 = a[64];       // ds_read2 (+64 dwords)
      a[0]  = r0 + (A.x - S);
      a[64] = r1 + S;                          // ib==64 -> guard bin 65
    }
  }

  __syncthreads();
  // flush: direct z-index sum of the 4 copies (guard bin 65 >= 4160 excluded);
  // accum stays bin-major [bin*64 + dir]; plain private-row stores (no atomics)
  float* __restrict__ obase = accum + blockIdx.x * ROWF;
  for (int z = tid; z < ROWF; z += THREADS)
    obase[z] = hist[z] + hist[HIST1 + z]
             + hist[2*HIST1 + z] + hist[3*HIST1 + z];
}

// 512 partial rows -> 64 rows; one output element per thread, coalesced
__global__ __launch_bounds__(256) void wect_reduceA(
    const float* __restrict__ accum, float* __restrict__ mid) {
  const int q = blockIdx.x * 256 + threadIdx.x;    // [0, 64*4160)
  if (q >= MROWS * ROWF) return;
  const int g = q / ROWF, z = q - g * ROWF;
  float v = 0.f;
  #pragma unroll
  for (int m = 0; m < NBLK / MROWS; ++m)           // 8 rows each
    v += accum[(g * (NBLK / MROWS) + m) * ROWF + z];
  mid[g * ROWF + z] = v;
}

__global__ __launch_bounds__(512) void wect_scan(
    const float* __restrict__ mid, float* __restrict__ out) {
  __shared__ float red[8 * NBIN];
  __shared__ float s[NBIN];
  const int k = blockIdx.x, tid = threadIdx.x;
  // mid is bin-major: element (row r, bin c, dir k) = mid[r*ROWF + c*64 + k]
  for (int z = tid; z < 8 * NBIN; z += 512) {   // 520 items > 512 thr: stride
    const int g = z / NBIN, c = z - g * NBIN;
    float v = 0.f;
    #pragma unroll
    for (int r = g; r < MROWS; r += 8) v += mid[r * ROWF + (c << 6) + k];
    red[z] = v;
  }
  __syncthreads();
  if (tid < NBIN) {
    float v = 0.f;
    #pragma unroll
    for (int gg = 0; gg < 8; ++gg) v += red[gg * NBIN + tid];
    s[tid] = v;
  }
  __syncthreads();
  for (int off = 1; off < NBIN; off <<= 1) {
    float a = 0.f;
    if (tid < NBIN && tid >= off) a = s[tid - off];
    __syncthreads();
    if (tid < NBIN && tid >= off) s[tid] += a;
    __syncthreads();
  }
  if (tid < NBIN) out[k * NBIN + tid] = s[tid];
}

extern "C" void kernel_launch(void* const* d_in, const int* in_sizes, int n_in,
                              void* d_out, int out_size, void* d_ws, size_t ws_size,
                              hipStream_t stream) {
  const float* x = (const float*)d_in[0];
  const float* dirs = (const float*)d_in[1];
  float* out = (float*)d_out;
  float* accum = (float*)d_ws;                 // 512*4160 floats = 8.5 MB
  float* mid = accum + NBLK * ROWF;            // 64*4160 floats = 1.06 MB

  wect_hist<<<NBLK, THREADS, 0, stream>>>(x, dirs, accum);
  wect_reduceA<<<(MROWS * ROWF + 255) / 256, 256, 0, stream>>>(accum, mid);
  wect_scan<<<NDIRS, 512, 0, stream>>>(mid, out);
}